// Round 1
// baseline (112.510 us; speedup 1.0000x reference)
//
#include <hip/hip_runtime.h>
#include <math.h>

#define NQ   12
#define NL   6
#define DIM  4096      // 2^12 amplitudes
#define BATCH 256
#define PI2  9.869604401089358f   // pi*pi

__device__ __forceinline__ float geluf(float x) {
    // exact gelu: 0.5*x*(1+erf(x/sqrt(2)))
    return 0.5f * x * (1.0f + erff(x * 0.70710678118654752f));
}

// LDS slot with +1-per-16 float2 padding: keeps quad-pass accesses
// conflict-free within each 16-lane phase (17-slot stride).
__device__ __forceinline__ int slotf(int j) { return j + (j >> 4); }

__device__ __forceinline__ float2 cmul(float2 a, float2 b) {
    return make_float2(fmaf(a.x, b.x, -a.y * b.y), fmaf(a.x, b.y, a.y * b.x));
}
__device__ __forceinline__ float2 cadd(float2 a, float2 b) {
    return make_float2(a.x + b.x, a.y + b.y);
}
__device__ __forceinline__ float2 cscale(float2 a, float s) {
    return make_float2(a.x * s, a.y * s);
}

__global__ __launch_bounds__(256)
void qpu_kernel(const float* __restrict__ x,   const float* __restrict__ W1, const float* __restrict__ b1,
                const float* __restrict__ g_ln, const float* __restrict__ b_ln,
                const float* __restrict__ W2,  const float* __restrict__ b2,
                const float* __restrict__ W3,  const float* __restrict__ b3,
                const float* __restrict__ qw,  const float* __restrict__ W4, const float* __restrict__ b4,
                const float* __restrict__ W5,  const float* __restrict__ b5,
                float* __restrict__ out)
{
    __shared__ float2 st[DIM + DIM / 16];   // 4352 float2 = 34,816 B (padded state)
    __shared__ float2 Um[NL * NQ * 4];      // 72 gates x 2x2 complex
    __shared__ float  xs[256];
    __shared__ float  h1n[128];
    __shared__ float  h2s[64];
    __shared__ float  xqs[NQ];
    __shared__ float  musd[2];
    __shared__ float  qv[3];
    __shared__ float  h4s[32];
    __shared__ float  zred[4][3];

    const int t = threadIdx.x;
    const int b = blockIdx.x;

    // ----------------- front-end MLP -----------------
    xs[t] = x[b * 256 + t];
    __syncthreads();

    // h1 = gelu(x @ W1.T + b1) : 128 outputs, dot-256
    if (t < 128) {
        const float4* w = (const float4*)(W1 + t * 256);
        float a0 = 0.f, a1 = 0.f, a2 = 0.f, a3 = 0.f;
        #pragma unroll 8
        for (int k = 0; k < 64; k++) {
            float4 wv = w[k];
            const float* xp = &xs[4 * k];
            a0 = fmaf(wv.x, xp[0], a0);
            a1 = fmaf(wv.y, xp[1], a1);
            a2 = fmaf(wv.z, xp[2], a2);
            a3 = fmaf(wv.w, xp[3], a3);
        }
        h1n[t] = geluf((a0 + a1) + (a2 + a3) + b1[t]);   // raw h1 for now
    }
    __syncthreads();

    // layernorm stats (wave 0 reduces 128 values)
    if (t < 64) {
        float v0 = h1n[t], v1 = h1n[t + 64];
        float s1 = v0 + v1;
        float s2 = fmaf(v0, v0, v1 * v1);
        #pragma unroll
        for (int off = 32; off > 0; off >>= 1) {
            s1 += __shfl_down(s1, off);
            s2 += __shfl_down(s2, off);
        }
        if (t == 0) {
            float mu  = s1 * (1.f / 128.f);
            float var = s2 * (1.f / 128.f) - mu * mu;
            musd[0] = mu;
            musd[1] = rsqrtf(var + 1e-5f);
        }
    }
    __syncthreads();
    if (t < 128) {
        h1n[t] = (h1n[t] - musd[0]) * musd[1] * g_ln[t] + b_ln[t];
    }
    __syncthreads();

    // h2 = gelu(h1n @ W2.T + b2) : 64 outputs, dot-128
    if (t < 64) {
        const float4* w = (const float4*)(W2 + t * 128);
        float a0 = 0.f, a1 = 0.f, a2 = 0.f, a3 = 0.f;
        #pragma unroll 8
        for (int k = 0; k < 32; k++) {
            float4 wv = w[k];
            const float* hp = &h1n[4 * k];
            a0 = fmaf(wv.x, hp[0], a0);
            a1 = fmaf(wv.y, hp[1], a1);
            a2 = fmaf(wv.z, hp[2], a2);
            a3 = fmaf(wv.w, hp[3], a3);
        }
        h2s[t] = geluf((a0 + a1) + (a2 + a3) + b2[t]);
    }
    __syncthreads();

    // xq = tanh(h2 @ W3.T + b3) : 12 outputs, dot-64
    if (t < NQ) {
        const float4* w = (const float4*)(W3 + t * 64);
        float a0 = 0.f, a1 = 0.f, a2 = 0.f, a3 = 0.f;
        #pragma unroll
        for (int k = 0; k < 16; k++) {
            float4 wv = w[k];
            const float* hp = &h2s[4 * k];
            a0 = fmaf(wv.x, hp[0], a0);
            a1 = fmaf(wv.y, hp[1], a1);
            a2 = fmaf(wv.z, hp[2], a2);
            a3 = fmaf(wv.w, hp[3], a3);
        }
        xqs[t] = tanhf((a0 + a1) + (a2 + a3) + b3[t]);
    }
    __syncthreads();

    // ----------------- gate matrices -----------------
    // U(l,i) = RZ(w2) RY(w1) RZ(w0); premultiplied by the preceding encoding
    // RY (initial encoding for l=0, mid-circuit 0.5*enc for l=1,3,5).
    if (t < NL * NQ) {
        const int l = t / NQ;
        const int i = t % NQ;
        float a  = qw[t * 3 + 0];
        float bb = qw[t * 3 + 1];
        float c  = qw[t * 3 + 2];
        float sb, cb;   sincosf(0.5f * bb, &sb, &cb);
        float apc = 0.5f * (a + c), amc = 0.5f * (a - c);
        float sapc, capc; sincosf(apc, &sapc, &capc);
        float samc, camc; sincosf(amc, &samc, &camc);
        float2 u00 = make_float2( cb * capc, -cb * sapc);
        float2 u01 = make_float2(-sb * camc, -sb * samc);
        float2 u10 = make_float2( sb * camc, -sb * samc);
        float2 u11 = make_float2( cb * capc,  cb * sapc);

        float theta = 0.f;
        bool merge = false;
        if (l == 0)      { theta = xqs[i] * PI2;        merge = true; }
        else if (l & 1)  { theta = xqs[i] * PI2 * 0.5f; merge = true; }
        if (merge) {
            float sy, cy; sincosf(0.5f * theta, &sy, &cy);
            float2 m00 = cadd(cscale(u00,  cy), cscale(u01, sy));
            float2 m01 = cadd(cscale(u00, -sy), cscale(u01, cy));
            float2 m10 = cadd(cscale(u10,  cy), cscale(u11, sy));
            float2 m11 = cadd(cscale(u10, -sy), cscale(u11, cy));
            u00 = m00; u01 = m01; u10 = m10; u11 = m11;
        }
        Um[t * 4 + 0] = u00;
        Um[t * 4 + 1] = u01;
        Um[t * 4 + 2] = u10;
        Um[t * 4 + 3] = u11;
    }

    // ----------------- init |0...0> -----------------
    #pragma unroll
    for (int m = 0; m < 16; m++) {
        st[slotf(t * 16 + m)] = make_float2(0.f, 0.f);
    }
    if (t == 0) st[slotf(0)] = make_float2(1.f, 0.f);
    __syncthreads();

    // ----------------- circuit -----------------
    for (int l = 0; l < NL; l++) {
        const float2* UL = &Um[l * NQ * 4];

        // three quad passes: gates on qubits (4c..4c+3), a contiguous bit
        // nibble at position P = 8-4c. Each thread owns one 16-amp subspace.
        #pragma unroll
        for (int c = 0; c < 3; c++) {
            const int P    = 8 - 4 * c;
            const int low  = t & ((1 << P) - 1);
            const int base = ((t >> P) << (P + 4)) | low;
            float2 a[16];
            #pragma unroll
            for (int m = 0; m < 16; m++) a[m] = st[slotf(base | (m << P))];
            #pragma unroll
            for (int q = 0; q < 4; q++) {
                const float2 u0 = UL[(4 * c + q) * 4 + 0];
                const float2 u1 = UL[(4 * c + q) * 4 + 1];
                const float2 u2 = UL[(4 * c + q) * 4 + 2];
                const float2 u3 = UL[(4 * c + q) * 4 + 3];
                const int bit = 8 >> q;   // qubit 4c+q <-> local bit (3-q)
                #pragma unroll
                for (int m = 0; m < 16; m++) {
                    if (m & bit) continue;
                    float2 x0 = a[m], x1 = a[m | bit];
                    a[m]       = cadd(cmul(u0, x0), cmul(u1, x1));
                    a[m | bit] = cadd(cmul(u2, x0), cmul(u3, x1));
                }
            }
            #pragma unroll
            for (int m = 0; m < 16; m++) st[slotf(base | (m << P))] = a[m];
            __syncthreads();
        }

        // CNOT ring as one linear gather; CZ layer fused as sign (odd layers)
        {
            float2 v[16];
            #pragma unroll
            for (int m = 0; m < 16; m++) {
                const int j = t * 16 + m;
                const int src = ((j ^ (j >> 1)) & 0x3FF)
                              | ((((j >> 10) ^ (j >> 11) ^ j) & 1) << 10)
                              | ((((j >> 11) ^ j) & 1) << 11);
                float2 val = st[slotf(src)];
                if (l & 1) {
                    const int cz = j & (j << 2) & 0xAA8;  // pairs (11,9)(9,7)(7,5)(5,3)(3,1)
                    if (__popc(cz) & 1) { val.x = -val.x; val.y = -val.y; }
                }
                v[m] = val;
            }
            __syncthreads();
            #pragma unroll
            for (int m = 0; m < 16; m++) st[slotf(t * 16 + m)] = v[m];
            __syncthreads();
        }
    }

    // ----------------- measurement: <Z> on qubits 0,1,2 -----------------
    float s = 0.f;
    #pragma unroll
    for (int m = 0; m < 16; m++) {
        float2 a = st[slotf(t * 16 + m)];
        s = fmaf(a.x, a.x, s);
        s = fmaf(a.y, a.y, s);
    }
    const int j0 = t * 16;               // bits 11,10,9 are constant per thread
    float z0 = (j0 & (1 << 11)) ? -s : s;
    float z1 = (j0 & (1 << 10)) ? -s : s;
    float z2 = (j0 & (1 <<  9)) ? -s : s;
    #pragma unroll
    for (int off = 32; off > 0; off >>= 1) {
        z0 += __shfl_down(z0, off);
        z1 += __shfl_down(z1, off);
        z2 += __shfl_down(z2, off);
    }
    if ((t & 63) == 0) {
        zred[t >> 6][0] = z0;
        zred[t >> 6][1] = z1;
        zred[t >> 6][2] = z2;
    }
    __syncthreads();
    if (t == 0) {
        qv[0] = zred[0][0] + zred[1][0] + zred[2][0] + zred[3][0];
        qv[1] = zred[0][1] + zred[1][1] + zred[2][1] + zred[3][1];
        qv[2] = zred[0][2] + zred[1][2] + zred[2][2] + zred[3][2];
    }
    __syncthreads();

    // ----------------- back-end MLP -----------------
    if (t < 32) {
        float h = b4[t];
        h = fmaf(qv[0], W4[t * 3 + 0], h);
        h = fmaf(qv[1], W4[t * 3 + 1], h);
        h = fmaf(qv[2], W4[t * 3 + 2], h);
        h4s[t] = geluf(h);
    }
    __syncthreads();
    if (t < 64) {
        float acc = b5[t];
        #pragma unroll
        for (int h = 0; h < 32; h++) acc = fmaf(h4s[h], W5[t * 32 + h], acc);
        out[b * 64 + t] = acc;
    }
}

extern "C" void kernel_launch(void* const* d_in, const int* in_sizes, int n_in,
                              void* d_out, int out_size, void* d_ws, size_t ws_size,
                              hipStream_t stream) {
    (void)in_sizes; (void)n_in; (void)d_ws; (void)ws_size; (void)out_size;
    const float* x    = (const float*)d_in[0];
    const float* W1   = (const float*)d_in[1];
    const float* b1   = (const float*)d_in[2];
    const float* g_ln = (const float*)d_in[3];
    const float* b_ln = (const float*)d_in[4];
    const float* W2   = (const float*)d_in[5];
    const float* b2   = (const float*)d_in[6];
    const float* W3   = (const float*)d_in[7];
    const float* b3   = (const float*)d_in[8];
    const float* qw   = (const float*)d_in[9];
    const float* W4   = (const float*)d_in[10];
    const float* b4   = (const float*)d_in[11];
    const float* W5   = (const float*)d_in[12];
    const float* b5   = (const float*)d_in[13];
    float* out = (float*)d_out;

    qpu_kernel<<<BATCH, 256, 0, stream>>>(x, W1, b1, g_ln, b_ln, W2, b2,
                                          W3, b3, qw, W4, b4, W5, b5, out);
}